// Round 1
// baseline (41.507 us; speedup 1.0000x reference)
//
#include <hip/hip_runtime.h>

#define B_ 4096
#define C_ 64
#define F_ 128

// ---------------------------------------------------------------------------
// Kernel A: e_bar[b][f] = (1/C) * sum_c emb[b][c][f]
// One block per batch. 256 threads: fc = t&31 (float4 column), cr = t>>5
// (row group, 8 rows each). float4 loads -> 16B/lane coalesced.
// ---------------------------------------------------------------------------
__global__ __launch_bounds__(256) void mean_kernel(const float* __restrict__ emb,
                                                   float* __restrict__ ebar) {
    const int b = blockIdx.x;
    const int t = threadIdx.x;
    const int fc = t & 31;   // float4 column index (32 per row)
    const int cr = t >> 5;   // row group 0..7

    const float4* src = (const float4*)(emb + (size_t)b * C_ * F_);
    float4 s = make_float4(0.f, 0.f, 0.f, 0.f);
    #pragma unroll
    for (int c = 0; c < C_ / 8; ++c) {
        float4 v = src[(cr + c * 8) * (F_ / 4) + fc];
        s.x += v.x; s.y += v.y; s.z += v.z; s.w += v.w;
    }

    __shared__ float4 part[8][32];
    part[cr][fc] = s;
    __syncthreads();
    if (t < 32) {
        float4 acc = part[0][t];
        #pragma unroll
        for (int i = 1; i < 8; ++i) {
            float4 v = part[i][t];
            acc.x += v.x; acc.y += v.y; acc.z += v.z; acc.w += v.w;
        }
        const float inv = 1.0f / (float)C_;
        acc.x *= inv; acc.y *= inv; acc.z *= inv; acc.w *= inv;
        ((float4*)(ebar + (size_t)b * F_))[t] = acc;
    }
}

// ---------------------------------------------------------------------------
// Kernel B: fused 4-layer MLP on [4096,128] rows.
//   h = relu(x@W0+b0); h = relu(h@W1+b1); h = relu(h@W2+b2); out = h@Wr+br
// 256 blocks x 16 rows. Per layer: stage W (128x128 f32, 64KB) in LDS,
// compute with 2 rows x 4 cols register blocking per thread.
// x rows live in 8KB LDS, updated in place between layers.
// ---------------------------------------------------------------------------
__global__ __launch_bounds__(256) void mlp_kernel(const float* __restrict__ xin,
                                                  const float* __restrict__ W0,
                                                  const float* __restrict__ b0,
                                                  const float* __restrict__ W1,
                                                  const float* __restrict__ b1,
                                                  const float* __restrict__ W2,
                                                  const float* __restrict__ b2,
                                                  const float* __restrict__ Wr,
                                                  const float* __restrict__ br,
                                                  float* __restrict__ out) {
    __shared__ float Wl[F_ * F_];      // 64 KB
    __shared__ float xb[16 * F_];      // 8 KB

    const int t   = threadIdx.x;
    const int cg  = t & 31;            // float4 col group: cols 4*cg..4*cg+3
    const int rg  = t >> 5;            // rows rg and rg+8
    const int row0 = blockIdx.x * 16;

    // initial x load: 512 float4, 2 per thread
    {
        const float4* src = (const float4*)(xin + (size_t)row0 * F_);
        float4* dst = (float4*)xb;
        dst[t]       = src[t];
        dst[t + 256] = src[t + 256];
    }

    const float4* xb4 = (const float4*)xb;
    const float4* Wl4 = (const float4*)Wl;

    const float* Ws[4] = {W0, W1, W2, Wr};
    const float* bs[4] = {b0, b1, b2, br};

    #pragma unroll
    for (int l = 0; l < 4; ++l) {
        __syncthreads();   // (A) xb writes of prev layer done; prev W reads done
        // stage W_l: 4096 float4, 16 per thread, coalesced
        {
            const float4* src = (const float4*)Ws[l];
            float4* dst = (float4*)Wl;
            #pragma unroll
            for (int i = 0; i < 16; ++i) dst[t + i * 256] = src[t + i * 256];
        }
        const float4 bias = ((const float4*)bs[l])[cg];
        __syncthreads();   // (B) W ready

        float acc0[4] = {0.f, 0.f, 0.f, 0.f};
        float acc1[4] = {0.f, 0.f, 0.f, 0.f};
        #pragma unroll 8
        for (int k4 = 0; k4 < 32; ++k4) {
            float4 xv0 = xb4[rg * 32 + k4];
            float4 xv1 = xb4[(rg + 8) * 32 + k4];
            const float xa[4]  = {xv0.x, xv0.y, xv0.z, xv0.w};
            const float xc[4]  = {xv1.x, xv1.y, xv1.z, xv1.w};
            #pragma unroll
            for (int i = 0; i < 4; ++i) {
                float4 w = Wl4[(k4 * 4 + i) * 32 + cg];
                acc0[0] += xa[i] * w.x; acc0[1] += xa[i] * w.y;
                acc0[2] += xa[i] * w.z; acc0[3] += xa[i] * w.w;
                acc1[0] += xc[i] * w.x; acc1[1] += xc[i] * w.y;
                acc1[2] += xc[i] * w.z; acc1[3] += xc[i] * w.w;
            }
        }

        float r0x = acc0[0] + bias.x, r0y = acc0[1] + bias.y;
        float r0z = acc0[2] + bias.z, r0w = acc0[3] + bias.w;
        float r1x = acc1[0] + bias.x, r1y = acc1[1] + bias.y;
        float r1z = acc1[2] + bias.z, r1w = acc1[3] + bias.w;

        if (l < 3) {
            r0x = fmaxf(r0x, 0.f); r0y = fmaxf(r0y, 0.f);
            r0z = fmaxf(r0z, 0.f); r0w = fmaxf(r0w, 0.f);
            r1x = fmaxf(r1x, 0.f); r1y = fmaxf(r1y, 0.f);
            r1z = fmaxf(r1z, 0.f); r1w = fmaxf(r1w, 0.f);
            __syncthreads();  // (C) all reads of xb for this layer done
            float4* xw = (float4*)xb;
            xw[rg * 32 + cg]       = make_float4(r0x, r0y, r0z, r0w);
            xw[(rg + 8) * 32 + cg] = make_float4(r1x, r1y, r1z, r1w);
        } else {
            float4* o = (float4*)(out + (size_t)row0 * F_);
            o[rg * 32 + cg]       = make_float4(r0x, r0y, r0z, r0w);
            o[(rg + 8) * 32 + cg] = make_float4(r1x, r1y, r1z, r1w);
        }
    }
}

extern "C" void kernel_launch(void* const* d_in, const int* in_sizes, int n_in,
                              void* d_out, int out_size, void* d_ws, size_t ws_size,
                              hipStream_t stream) {
    const float* emb = (const float*)d_in[0];
    const float* W0  = (const float*)d_in[1];
    const float* b0  = (const float*)d_in[2];
    const float* W1  = (const float*)d_in[3];
    const float* b1  = (const float*)d_in[4];
    const float* W2  = (const float*)d_in[5];
    const float* b2  = (const float*)d_in[6];
    const float* Wr  = (const float*)d_in[7];
    const float* br  = (const float*)d_in[8];

    float* ebar = (float*)d_ws;  // 4096*128*4 = 2 MB scratch

    mean_kernel<<<B_, 256, 0, stream>>>(emb, ebar);
    mlp_kernel<<<B_ / 16, 256, 0, stream>>>(ebar, W0, b0, W1, b1, W2, b2,
                                            Wr, br, (float*)d_out);
}